// Round 16
// baseline (24.031 us; speedup 1.0000x reference)
//
#include <hip/hip_runtime.h>

#define NH 8
#define LQ 32
#define XW_LO 166            // x window rows [166,186] (center 176)
#define YW_LO 190            // y window rows [190,210] (center 200)
#define WN 21                // rows per axis window; z = [0,20] fully covered
#define NROWS 63             // 63 rows x 128 f16 (256B) = 16.1 KB LDS

typedef float    f32x4 __attribute__((ext_vector_type(4)));
typedef _Float16 f16x4 __attribute__((ext_vector_type(4)));
typedef _Float16 f16x2 __attribute__((ext_vector_type(2)));
typedef _Float16 f16x8 __attribute__((ext_vector_type(8)));

__device__ __forceinline__ f16x4 cvt4(f32x4 g) {
    return (f16x4){(_Float16)g.x, (_Float16)g.y, (_Float16)g.z, (_Float16)g.w};
}

__device__ __forceinline__ f16x8 cvt8(f32x4 a, f32x4 b) {
    return (f16x8){(_Float16)a.x, (_Float16)a.y, (_Float16)a.z, (_Float16)a.w,
                   (_Float16)b.x, (_Float16)b.y, (_Float16)b.z, (_Float16)b.w};
}

__device__ __forceinline__ float dot8h(f16x8 a, f16x8 b) {
    f16x2 a0 = __builtin_shufflevector(a, a, 0, 1);
    f16x2 a1 = __builtin_shufflevector(a, a, 2, 3);
    f16x2 a2 = __builtin_shufflevector(a, a, 4, 5);
    f16x2 a3 = __builtin_shufflevector(a, a, 6, 7);
    f16x2 b0 = __builtin_shufflevector(b, b, 0, 1);
    f16x2 b1 = __builtin_shufflevector(b, b, 2, 3);
    f16x2 b2 = __builtin_shufflevector(b, b, 4, 5);
    f16x2 b3 = __builtin_shufflevector(b, b, 6, 7);
#if __has_builtin(__builtin_amdgcn_fdot2)
    float c = __builtin_amdgcn_fdot2(a3, b3, 0.0f, false);
    c = __builtin_amdgcn_fdot2(a2, b2, c, false);
    c = __builtin_amdgcn_fdot2(a1, b1, c, false);
    c = __builtin_amdgcn_fdot2(a0, b0, c, false);
    return c;
#else
    return (float)a0.x*(float)b0.x + (float)a0.y*(float)b0.y
         + (float)a1.x*(float)b1.x + (float)a1.y*(float)b1.y
         + (float)a2.x*(float)b2.x + (float)a2.y*(float)b2.y
         + (float)a3.x*(float)b3.x + (float)a3.y*(float)b3.y;
#endif
}

__global__ __launch_bounds__(512) void rpe_kernel(
    const float* __restrict__ relpos,
    const float* __restrict__ qfeat,
    const float* __restrict__ scaling,
    const float* __restrict__ tx,
    const float* __restrict__ ty,
    const float* __restrict__ tz,
    float* __restrict__ out, int N)
{
    __shared__ alignas(16) _Float16 W[NROWS * 128];   // rows of 128 f16 (256B)

    const int t = threadIdx.x;

    // ---- stage hot window -> LDS as f16 (63 rows x 32 pieces of 4 f32) ----
#pragma unroll
    for (int i = 0; i < 4; ++i) {
        int c = t + i * 512;
        if (c < NROWS * 32) {
            int r = c >> 5, p = c & 31;
            const float* src;
            if (r < WN)          src = tx + (size_t)(XW_LO + r) * 128 + p * 4;
            else if (r < 2*WN)   src = ty + (size_t)(YW_LO + (r - WN)) * 128 + p * 4;
            else                 src = tz + (size_t)(r - 2*WN) * 128 + p * 4;
            *(f16x4*)&W[r * 128 + p * 4] = cvt4(*(const f32x4*)src);
        }
    }
    __syncthreads();

    // ---- mapping: wave = one n; lane owns 8 f16 dims (16B) of one head ----
    const int lane = t & 63;
    const int w    = t >> 6;              // wave 0..7
    const int gn   = blockIdx.x * 8 + w;  // N = 20000 = 2500*8, always valid
    const int g    = (lane >> 4) & 3;     // 16-lane row-group
    const int k15  = lane & 15;           // lane's 16B piece within a row
    const int head = k15 >> 1;
    const int p    = lane & 1;            // low/high 8 dims of the head
    const int loff = (g & 1) | ((g & 2) << 3);   // group's l offset: 0,1,16,17

    // lane computes packed idx for l = lane&31 (upper half duplicates)
    const float* rp = relpos + ((size_t)gn * LQ + (lane & 31)) * 3;
    float rx = rp[0], ry = rp[1], rz = rp[2];
    // XLA semantics: /0.4f canonicalized to *2.5f (exact), f32 add (R4-verified)
    int ix = min(max((int)floorf((rx + 70.4f) * 2.5f), 0), 352);
    int iy = min(max((int)floorf((ry + 80.0f) * 2.5f), 0), 400);
    int iz = min(max((int)floorf((rz + 4.0f)  * 2.5f), 0), 20);
    unsigned packed = (unsigned)ix | ((unsigned)iy << 9) | ((unsigned)iz << 18);

    // hoist ALL cross-lane index fetches out of the loop: their DS latencies
    // overlap here instead of heading each iteration's dependency chain
    unsigned pk[8];
#pragma unroll
    for (int i = 0; i < 8; ++i)
        pk[i] = (unsigned)__shfl((int)packed, 2 * i + loff, 64);

    // qf: this lane's 8 dims per axis, converted once to f16
    const float* qb = qfeat + (size_t)gn * (NH * 48) + head * 48 + p * 8;
    f16x8 qx = cvt8(*(const f32x4*)(qb),      *(const f32x4*)(qb + 4));
    f16x8 qy = cvt8(*(const f32x4*)(qb + 16), *(const f32x4*)(qb + 20));
    f16x8 qz = cvt8(*(const f32x4*)(qb + 32), *(const f32x4*)(qb + 36));

    const float s = scaling[0];
    const char* txb = (const char*)tx + k15 * 32;   // fallback piece base (f32)
    const char* tyb = (const char*)ty + k15 * 32;
    const _Float16* Wl = W + k15 * 8;               // lane's piece within any row
    float* outp = out + (size_t)gn * (LQ * NH);

#pragma unroll 4
    for (int i = 0; i < 8; ++i) {
        int l = 2 * i + loff;                       // this group's l
        unsigned jx = pk[i] & 511u;
        unsigned jy = (pk[i] >> 9) & 511u;
        unsigned jz = pk[i] >> 18;

        f16x8 ax, ay, az;
        unsigned ox = jx - XW_LO;      // unsigned wrap: in-window iff < WN
        if (ox < WN) ax = *(const f16x8*)(Wl + ox * 128);
        else {                         // rare exact fallback (f32 row in global)
            const char* gp = txb + ((size_t)jx << 9);
            ax = cvt8(*(const f32x4*)gp, *(const f32x4*)(gp + 16));
        }
        unsigned oy = jy - YW_LO;
        if (oy < WN) ay = *(const f16x8*)(Wl + (WN + oy) * 128);
        else {
            const char* gp = tyb + ((size_t)jy << 9);
            ay = cvt8(*(const f32x4*)gp, *(const f32x4*)(gp + 16));
        }
        az = *(const f16x8*)(Wl + (2 * WN + jz) * 128);   // always staged

        float acc = (dot8h(ax, qx) + dot8h(ay, qy)) + dot8h(az, qz);

        // head = 2 lanes -> single DPP pair-swap reduce
        int d = __builtin_amdgcn_update_dpp(0, __float_as_int(acc),
                                            0xB1, 0xF, 0xF, true); // [1,0,3,2]
        acc += __int_as_float(d);

        if (p == 0) outp[l * NH + head] = acc * s;
    }
}

extern "C" void kernel_launch(void* const* d_in, const int* in_sizes, int n_in,
                              void* d_out, int out_size, void* d_ws, size_t ws_size,
                              hipStream_t stream) {
    const float* relpos  = (const float*)d_in[0];
    const float* qfeat   = (const float*)d_in[1];
    const float* scaling = (const float*)d_in[2];
    // d_in[3] = query_batch_cnt (unused by reference math)
    const float* tx      = (const float*)d_in[4];
    const float* ty      = (const float*)d_in[5];
    const float* tz      = (const float*)d_in[6];
    float* out           = (float*)d_out;

    int N = in_sizes[0] / (LQ * 3);   // 20000
    int blocks = (N + 7) / 8;         // 2500

    rpe_kernel<<<blocks, 512, 0, stream>>>(relpos, qfeat, scaling, tx, ty, tz, out, N);
}

// Round 17
// 21.503 us; speedup vs baseline: 1.1176x; 1.1176x over previous
//
#include <hip/hip_runtime.h>

#define NH 8
#define LQ 32
#define XW_LO 166            // x window rows [166,186] (center 176)
#define YW_LO 190            // y window rows [190,210] (center 200)
#define WN 21                // rows per axis window; z = [0,20] fully covered
#define NROWS 63             // 63 rows x 128 f16 (256B) = 16.1 KB LDS
#define NBLK 1024            // persistent: 4 blocks/CU x 256 CU
#define NSTR (NBLK * 8)      // n-stride per wave = 8192

typedef float    f32x4 __attribute__((ext_vector_type(4)));
typedef _Float16 f16x4 __attribute__((ext_vector_type(4)));
typedef _Float16 f16x2 __attribute__((ext_vector_type(2)));
typedef _Float16 f16x8 __attribute__((ext_vector_type(8)));

__device__ __forceinline__ f16x4 cvt4(f32x4 g) {
    return (f16x4){(_Float16)g.x, (_Float16)g.y, (_Float16)g.z, (_Float16)g.w};
}

__device__ __forceinline__ f16x8 cvt8(f32x4 a, f32x4 b) {
    return (f16x8){(_Float16)a.x, (_Float16)a.y, (_Float16)a.z, (_Float16)a.w,
                   (_Float16)b.x, (_Float16)b.y, (_Float16)b.z, (_Float16)b.w};
}

__device__ __forceinline__ float dot8h(f16x8 a, f16x8 b) {
    f16x2 a0 = __builtin_shufflevector(a, a, 0, 1);
    f16x2 a1 = __builtin_shufflevector(a, a, 2, 3);
    f16x2 a2 = __builtin_shufflevector(a, a, 4, 5);
    f16x2 a3 = __builtin_shufflevector(a, a, 6, 7);
    f16x2 b0 = __builtin_shufflevector(b, b, 0, 1);
    f16x2 b1 = __builtin_shufflevector(b, b, 2, 3);
    f16x2 b2 = __builtin_shufflevector(b, b, 4, 5);
    f16x2 b3 = __builtin_shufflevector(b, b, 6, 7);
#if __has_builtin(__builtin_amdgcn_fdot2)
    float c = __builtin_amdgcn_fdot2(a3, b3, 0.0f, false);
    c = __builtin_amdgcn_fdot2(a2, b2, c, false);
    c = __builtin_amdgcn_fdot2(a1, b1, c, false);
    c = __builtin_amdgcn_fdot2(a0, b0, c, false);
    return c;
#else
    return (float)a0.x*(float)b0.x + (float)a0.y*(float)b0.y
         + (float)a1.x*(float)b1.x + (float)a1.y*(float)b1.y
         + (float)a2.x*(float)b2.x + (float)a2.y*(float)b2.y
         + (float)a3.x*(float)b3.x + (float)a3.y*(float)b3.y;
#endif
}

__global__ __launch_bounds__(512) void rpe_kernel(
    const float* __restrict__ relpos,
    const float* __restrict__ qfeat,
    const float* __restrict__ scaling,
    const float* __restrict__ tx,
    const float* __restrict__ ty,
    const float* __restrict__ tz,
    float* __restrict__ out, int N)
{
    __shared__ alignas(16) _Float16 W[NROWS * 128];   // rows of 128 f16 (256B)

    const int t = threadIdx.x;

    // ---- stage hot window -> LDS as f16, ONCE per persistent block ----
#pragma unroll
    for (int i = 0; i < 4; ++i) {
        int c = t + i * 512;
        if (c < NROWS * 32) {
            int r = c >> 5, pc = c & 31;
            const float* src;
            if (r < WN)          src = tx + (size_t)(XW_LO + r) * 128 + pc * 4;
            else if (r < 2*WN)   src = ty + (size_t)(YW_LO + (r - WN)) * 128 + pc * 4;
            else                 src = tz + (size_t)(r - 2*WN) * 128 + pc * 4;
            *(f16x4*)&W[r * 128 + pc * 4] = cvt4(*(const f32x4*)src);
        }
    }
    __syncthreads();

    // ---- mapping: wave = one n per trip; lane owns 8 f16 dims of one head ----
    const int lane = t & 63;
    const int g    = (lane >> 4) & 3;     // 16-lane row-group
    const int k15  = lane & 15;           // lane's 16B piece within a row
    const int head = k15 >> 1;
    const int p    = lane & 1;            // low/high 8 dims of the head
    const int loff = (g & 1) | ((g & 2) << 3);   // group's l offset: 0,1,16,17
    const int lsel = lane & 31;           // idx source lane

    const float s = scaling[0];
    const char* txb = (const char*)tx + k15 * 32;   // fallback piece base (f32)
    const char* tyb = (const char*)ty + k15 * 32;
    const _Float16* Wl = W + k15 * 8;               // lane's piece in any row

    int gn = blockIdx.x * 8 + (t >> 6);
    if (gn >= N) return;                  // (after barrier; all valid at N=20000)

    // first n's relpos (subsequent trips use the prefetched copy)
    const float* rp = relpos + ((size_t)gn * LQ + lsel) * 3;
    float rx = rp[0], ry = rp[1], rz = rp[2];

    while (true) {
        // qf loads issued early: latency hides under idx math + cvt
        const float* qb = qfeat + (size_t)gn * (NH * 48) + head * 48 + p * 8;
        f32x4 q0 = *(const f32x4*)(qb);
        f32x4 q1 = *(const f32x4*)(qb + 4);
        f32x4 q2 = *(const f32x4*)(qb + 16);
        f32x4 q3 = *(const f32x4*)(qb + 20);
        f32x4 q4 = *(const f32x4*)(qb + 32);
        f32x4 q5 = *(const f32x4*)(qb + 36);

        // XLA semantics: /0.4f canonicalized to *2.5f (exact), f32 add (R4-verified)
        int ix = min(max((int)floorf((rx + 70.4f) * 2.5f), 0), 352);
        int iy = min(max((int)floorf((ry + 80.0f) * 2.5f), 0), 400);
        int iz = min(max((int)floorf((rz + 4.0f)  * 2.5f), 0), 20);
        unsigned packed = (unsigned)ix | ((unsigned)iy << 9) | ((unsigned)iz << 18);

        // prefetch next n's relpos (overlaps the inner DS loop)
        int gn_next = gn + NSTR;
        bool more = gn_next < N;
        {
            int gl = more ? gn_next : gn;
            const float* rpn = relpos + ((size_t)gl * LQ + lsel) * 3;
            rx = rpn[0]; ry = rpn[1]; rz = rpn[2];
        }

        f16x8 qx = cvt8(q0, q1);
        f16x8 qy = cvt8(q2, q3);
        f16x8 qz = cvt8(q4, q5);

        float* outp = out + (size_t)gn * (LQ * NH);

#pragma unroll 4
        for (int i = 0; i < 8; ++i) {
            int l = 2 * i + loff;                       // this group's l
            unsigned pk = (unsigned)__shfl((int)packed, l, 64);
            unsigned jx = pk & 511u;
            unsigned jy = (pk >> 9) & 511u;
            unsigned jz = pk >> 18;

            f16x8 ax, ay, az;
            unsigned ox = jx - XW_LO;      // unsigned wrap: in-window iff < WN
            if (ox < WN) ax = *(const f16x8*)(Wl + ox * 128);
            else {                         // rare exact fallback (f32 global row)
                const char* gp = txb + ((size_t)jx << 9);
                ax = cvt8(*(const f32x4*)gp, *(const f32x4*)(gp + 16));
            }
            unsigned oy = jy - YW_LO;
            if (oy < WN) ay = *(const f16x8*)(Wl + (WN + oy) * 128);
            else {
                const char* gp = tyb + ((size_t)jy << 9);
                ay = cvt8(*(const f32x4*)gp, *(const f32x4*)(gp + 16));
            }
            az = *(const f16x8*)(Wl + (2 * WN + jz) * 128);   // always staged

            float acc = (dot8h(ax, qx) + dot8h(ay, qy)) + dot8h(az, qz);

            // head = 2 lanes -> single DPP pair-swap reduce
            int d = __builtin_amdgcn_update_dpp(0, __float_as_int(acc),
                                                0xB1, 0xF, 0xF, true); // [1,0,3,2]
            acc += __int_as_float(d);

            if (p == 0) outp[l * NH + head] = acc * s;
        }

        if (!more) break;
        gn = gn_next;
    }
}

extern "C" void kernel_launch(void* const* d_in, const int* in_sizes, int n_in,
                              void* d_out, int out_size, void* d_ws, size_t ws_size,
                              hipStream_t stream) {
    const float* relpos  = (const float*)d_in[0];
    const float* qfeat   = (const float*)d_in[1];
    const float* scaling = (const float*)d_in[2];
    // d_in[3] = query_batch_cnt (unused by reference math)
    const float* tx      = (const float*)d_in[4];
    const float* ty      = (const float*)d_in[5];
    const float* tz      = (const float*)d_in[6];
    float* out           = (float*)d_out;

    int N = in_sizes[0] / (LQ * 3);   // 20000
    int blocks = (N + 7) / 8;         // upper bound on useful blocks
    if (blocks > NBLK) blocks = NBLK; // persistent: 1024 = 4 blocks/CU

    rpe_kernel<<<blocks, 512, 0, stream>>>(relpos, qfeat, scaling, tx, ty, tz, out, N);
}

// Round 18
// 20.346 us; speedup vs baseline: 1.1811x; 1.0569x over previous
//
#include <hip/hip_runtime.h>

#define NH 8
#define LQ 32
#define XW_LO 166            // x window rows [166,186] (center 176)
#define YW_LO 190            // y window rows [190,210] (center 200)
#define WN 21                // rows per axis window; z = [0,20] fully covered
#define NROWS 63             // 63 rows x 128 f16 (256B) = 16.1 KB LDS
#define NBLK 1024            // persistent: 4 blocks/CU x 256 CU
#define NSTR (NBLK * 8)      // n-stride per wave = 8192

typedef float    f32x4 __attribute__((ext_vector_type(4)));
typedef _Float16 f16x4 __attribute__((ext_vector_type(4)));
typedef _Float16 f16x2 __attribute__((ext_vector_type(2)));
typedef _Float16 f16x8 __attribute__((ext_vector_type(8)));

__device__ __forceinline__ f16x4 cvt4(f32x4 g) {
    return (f16x4){(_Float16)g.x, (_Float16)g.y, (_Float16)g.z, (_Float16)g.w};
}

__device__ __forceinline__ f16x8 cvt8(f32x4 a, f32x4 b) {
    return (f16x8){(_Float16)a.x, (_Float16)a.y, (_Float16)a.z, (_Float16)a.w,
                   (_Float16)b.x, (_Float16)b.y, (_Float16)b.z, (_Float16)b.w};
}

__device__ __forceinline__ float dot8h(f16x8 a, f16x8 b) {
    f16x2 a0 = __builtin_shufflevector(a, a, 0, 1);
    f16x2 a1 = __builtin_shufflevector(a, a, 2, 3);
    f16x2 a2 = __builtin_shufflevector(a, a, 4, 5);
    f16x2 a3 = __builtin_shufflevector(a, a, 6, 7);
    f16x2 b0 = __builtin_shufflevector(b, b, 0, 1);
    f16x2 b1 = __builtin_shufflevector(b, b, 2, 3);
    f16x2 b2 = __builtin_shufflevector(b, b, 4, 5);
    f16x2 b3 = __builtin_shufflevector(b, b, 6, 7);
#if __has_builtin(__builtin_amdgcn_fdot2)
    float c = __builtin_amdgcn_fdot2(a3, b3, 0.0f, false);
    c = __builtin_amdgcn_fdot2(a2, b2, c, false);
    c = __builtin_amdgcn_fdot2(a1, b1, c, false);
    c = __builtin_amdgcn_fdot2(a0, b0, c, false);
    return c;
#else
    return (float)a0.x*(float)b0.x + (float)a0.y*(float)b0.y
         + (float)a1.x*(float)b1.x + (float)a1.y*(float)b1.y
         + (float)a2.x*(float)b2.x + (float)a2.y*(float)b2.y
         + (float)a3.x*(float)b3.x + (float)a3.y*(float)b3.y;
#endif
}

__global__ __launch_bounds__(512) void rpe_kernel(
    const float* __restrict__ relpos,
    const float* __restrict__ qfeat,
    const float* __restrict__ scaling,
    const float* __restrict__ tx,
    const float* __restrict__ ty,
    const float* __restrict__ tz,
    float* __restrict__ out, int N)
{
    __shared__ alignas(16) _Float16 W[NROWS * 128];   // rows of 128 f16 (256B)

    const int t = threadIdx.x;

    // ---- stage hot window -> LDS as f16, ONCE per persistent block ----
#pragma unroll
    for (int i = 0; i < 4; ++i) {
        int c = t + i * 512;
        if (c < NROWS * 32) {
            int r = c >> 5, pc = c & 31;
            const float* src;
            if (r < WN)          src = tx + (size_t)(XW_LO + r) * 128 + pc * 4;
            else if (r < 2*WN)   src = ty + (size_t)(YW_LO + (r - WN)) * 128 + pc * 4;
            else                 src = tz + (size_t)(r - 2*WN) * 128 + pc * 4;
            *(f16x4*)&W[r * 128 + pc * 4] = cvt4(*(const f32x4*)src);
        }
    }
    __syncthreads();

    // ---- mapping: wave = one n per trip; lane owns 8 f16 dims of one head ----
    const int lane = t & 63;
    const int g    = (lane >> 4) & 3;     // 16-lane row-group
    const int k15  = lane & 15;           // lane's 16B piece within a row
    const int head = k15 >> 1;
    const int p    = lane & 1;            // low/high 8 dims of the head
    const int loff = (g & 1) | ((g & 2) << 3);   // group's l offset: 0,1,16,17
    const int lsel = lane & 31;           // idx source lane

    const float s = scaling[0];
    const char* txb = (const char*)tx + k15 * 32;    // fallback piece base (f32)
    const char* tyb = (const char*)ty + k15 * 32;
    const _Float16* Wlx = W + k15 * 8;               // lane's piece, x rows
    const _Float16* Wly = Wlx + WN * 128;            // y rows
    const _Float16* Wlz = Wlx + 2 * WN * 128;        // z rows

    int gn = blockIdx.x * 8 + (t >> 6);
    if (gn >= N) return;                  // (after barrier; all valid at N=20000)

    // first n's relpos (subsequent trips use the prefetched copy)
    const float* rp = relpos + ((size_t)gn * LQ + lsel) * 3;
    float rx = rp[0], ry = rp[1], rz = rp[2];

    while (true) {
        // qf loads issued early: latency hides under idx math + cvt
        const float* qb = qfeat + (size_t)gn * (NH * 48) + head * 48 + p * 8;
        f32x4 q0 = *(const f32x4*)(qb);
        f32x4 q1 = *(const f32x4*)(qb + 4);
        f32x4 q2 = *(const f32x4*)(qb + 16);
        f32x4 q3 = *(const f32x4*)(qb + 20);
        f32x4 q4 = *(const f32x4*)(qb + 32);
        f32x4 q5 = *(const f32x4*)(qb + 36);

        // XLA semantics: /0.4f canonicalized to *2.5f (exact), f32 add (R4-verified)
        int ix = min(max((int)floorf((rx + 70.4f) * 2.5f), 0), 352);
        int iy = min(max((int)floorf((ry + 80.0f) * 2.5f), 0), 400);
        int iz = min(max((int)floorf((rz + 4.0f)  * 2.5f), 0), 20);
        unsigned packed = (unsigned)ix | ((unsigned)iy << 9) | ((unsigned)iz << 18);

        // prefetch next n's relpos (overlaps the inner DS loop)
        int gn_next = gn + NSTR;
        bool more = gn_next < N;
        {
            int gl = more ? gn_next : gn;
            const float* rpn = relpos + ((size_t)gl * LQ + lsel) * 3;
            rx = rpn[0]; ry = rpn[1]; rz = rpn[2];
        }

        f16x8 qx = cvt8(q0, q1);
        f16x8 qy = cvt8(q2, q3);
        f16x8 qz = cvt8(q4, q5);

        float* outp = out + (size_t)gn * (LQ * NH);

#pragma unroll 2
        for (int i = 0; i < 8; i += 2) {
            float acc0, acc1;
#pragma unroll
            for (int u = 0; u < 2; ++u) {
                int l = 2 * (i + u) + loff;                 // this group's l
                unsigned pk = (unsigned)__shfl((int)packed, l, 64);
                unsigned jx = pk & 511u;
                unsigned jy = (pk >> 9) & 511u;
                unsigned jz = pk >> 18;
                unsigned ox = jx - XW_LO;    // unsigned wrap: in-window iff < WN
                unsigned oy = jy - YW_LO;

                f16x8 ax, ay, az;
                if (__builtin_expect(__any((ox >= WN) || (oy >= WN)), 0)) {
                    // rare wave-uniform slow path: exact, in-window lanes read
                    // the same LDS bytes as the fast path -> identical results
                    if (ox < WN) ax = *(const f16x8*)(Wlx + ox * 128);
                    else {
                        const char* gp = txb + ((size_t)jx << 9);
                        ax = cvt8(*(const f32x4*)gp, *(const f32x4*)(gp + 16));
                    }
                    if (oy < WN) ay = *(const f16x8*)(Wly + oy * 128);
                    else {
                        const char* gp = tyb + ((size_t)jy << 9);
                        ay = cvt8(*(const f32x4*)gp, *(const f32x4*)(gp + 16));
                    }
                } else {
                    // fast path: unconditional LDS reads, no exec-mask juggling
                    ax = *(const f16x8*)(Wlx + ox * 128);
                    ay = *(const f16x8*)(Wly + oy * 128);
                }
                az = *(const f16x8*)(Wlz + jz * 128);       // always staged

                float acc = (dot8h(ax, qx) + dot8h(ay, qy)) + dot8h(az, qz);
                // head = 2 lanes -> DPP pair-swap: BOTH lanes get the full sum
                int d = __builtin_amdgcn_update_dpp(0, __float_as_int(acc),
                                                    0xB1, 0xF, 0xF, true);
                acc += __int_as_float(d);
                if (u == 0) acc0 = acc * s; else acc1 = acc * s;
            }
            // paired store: p=0 lane stores iter i, p=1 lane stores iter i+1;
            // all 64 lanes store -> half the store instrs, no predication
            int lst = 2 * i + 2 * p + loff;
            float v = p ? acc1 : acc0;
            outp[lst * NH + head] = v;
        }

        if (!more) break;
        gn = gn_next;
    }
}

extern "C" void kernel_launch(void* const* d_in, const int* in_sizes, int n_in,
                              void* d_out, int out_size, void* d_ws, size_t ws_size,
                              hipStream_t stream) {
    const float* relpos  = (const float*)d_in[0];
    const float* qfeat   = (const float*)d_in[1];
    const float* scaling = (const float*)d_in[2];
    // d_in[3] = query_batch_cnt (unused by reference math)
    const float* tx      = (const float*)d_in[4];
    const float* ty      = (const float*)d_in[5];
    const float* tz      = (const float*)d_in[6];
    float* out           = (float*)d_out;

    int N = in_sizes[0] / (LQ * 3);   // 20000
    int blocks = (N + 7) / 8;         // upper bound on useful blocks
    if (blocks > NBLK) blocks = NBLK; // persistent: 1024 = 4 blocks/CU

    rpe_kernel<<<blocks, 512, 0, stream>>>(relpos, qfeat, scaling, tx, ty, tz, out, N);
}